// Round 2
// baseline (122.401 us; speedup 1.0000x reference)
//
#include <hip/hip_runtime.h>
#include <hip/hip_bf16.h>

#define B_ 32
#define T_ 8192
#define F_ 256
#define H_ 128

typedef short bf16x8 __attribute__((ext_vector_type(8)));
typedef float f32x4  __attribute__((ext_vector_type(4)));

// float -> bf16 round-to-nearest-even (normal values; inputs are Gaussian)
static __device__ __forceinline__ unsigned int f2bf(float x) {
    unsigned int u = __builtin_bit_cast(unsigned int, x);
    u += 0x7fffu + ((u >> 16) & 1u);
    return u >> 16;
}
static __device__ __forceinline__ unsigned int pack_bf2(float lo, float hi) {
    return f2bf(lo) | (f2bf(hi) << 16);
}

// ws layout: [0, 16KB): w2d = dec@W2, fp32 [32][128]
//            [16KB, 80KB): W1 bf16 fragments, 4096 entries * 16B
// Fragment entry e = (nt*8 + ks)*64 + lane ; entry[j] = bf16(W1[f][h])
//   with q = lane>>4, c = lane&15, h = 16*nt + c, f = 64*q + 8*ks + j
__global__ __launch_bounds__(256) void prep_kernel(const float* __restrict__ dec,
                                                   const float* __restrict__ W1,
                                                   const float* __restrict__ W2,
                                                   float* __restrict__ w2d,
                                                   uint4* __restrict__ frags) {
    const int blk = blockIdx.x, tid = threadIdx.x;
    if (blk < 32) {
        // w2d[b][h] = sum_f dec[b][f] * W2[f][h]   (fp32 exact path)
        if (tid < H_) {
            const float* dp = dec + blk * F_;
            float s = 0.f;
            #pragma unroll 8
            for (int f = 0; f < F_; ++f) s += dp[f] * W2[f * H_ + tid];
            w2d[blk * H_ + tid] = s;
        }
    } else {
        const int e = (blk - 32) * 256 + tid;   // 0..4095
        const int lane = e & 63;
        const int ks   = (e >> 6) & 7;
        const int nt   = e >> 9;
        const int q = lane >> 4, c = lane & 15;
        const int h = nt * 16 + c;
        const float* src = W1 + (q * 64 + ks * 8) * H_ + h;
        unsigned int u[4];
        #pragma unroll
        for (int jj = 0; jj < 4; ++jj) {
            float a = src[(2 * jj) * H_];
            float b = src[(2 * jj + 1) * H_];
            u[jj] = pack_bf2(a, b);
        }
        frags[e] = uint4{u[0], u[1], u[2], u[3]};
    }
}

// Main: 512 blocks x 256 threads. Block -> (b = blk>>4, t0 = (blk&15)*512).
// 8 iters x 64 rows (4 waves x 16 rows). Wave does 16 rows x 128 cols, K=256.
__global__ __launch_bounds__(256) void attn_main(const float* __restrict__ enc,
                                                 const float* __restrict__ Vvec,
                                                 const float* __restrict__ w2d,
                                                 const uint4* __restrict__ frags,
                                                 float* __restrict__ out) {
    __shared__ uint4 lds_frags[4096];   // 64 KB: W1 bf16 fragments
    const int tid = threadIdx.x;

    // One-time stage of W1 fragments (linear, coalesced)
    #pragma unroll
    for (int i = 0; i < 16; ++i) lds_frags[tid + i * 256] = frags[tid + i * 256];

    const int blk = blockIdx.x;
    const int b  = blk >> 4;
    const int t0 = (blk & 15) << 9;
    const int w    = tid >> 6;
    const int lane = tid & 63;
    const int q = lane >> 4;      // A: k-quarter; D: row-group
    const int c = lane & 15;      // A: row; D: col-within-ntile

    // Per-lane epilogue constants: V[h] and w2d[b][h] for h = 16*nt + c
    float Vv[8], w2dv[8];
    #pragma unroll
    for (int nt = 0; nt < 8; ++nt) {
        Vv[nt]   = Vvec[nt * 16 + c];
        w2dv[nt] = w2d[b * H_ + nt * 16 + c];
    }
    __syncthreads();

    const bf16x8* bl = (const bf16x8*)lds_frags;

    for (int it = 0; it < 8; ++it) {
        const int tbase = t0 + it * 64 + w * 16;
        const int trow  = tbase + c;
        // Lane reads 64 contiguous fp32: enc[b][trow][q*64 .. q*64+64)
        const f32x4* rp = (const f32x4*)(enc + ((size_t)b * T_ + trow) * F_ + q * 64);
        f32x4 x[16];
        #pragma unroll
        for (int i = 0; i < 16; ++i) x[i] = rp[i];

        // Convert to A fragments: af[ks][j] = bf16(row[64q + 8ks + j])
        bf16x8 af[8];
        #pragma unroll
        for (int ks = 0; ks < 8; ++ks) {
            union { bf16x8 v; unsigned int u[4]; } pk;
            pk.u[0] = pack_bf2(x[2 * ks][0],     x[2 * ks][1]);
            pk.u[1] = pack_bf2(x[2 * ks][2],     x[2 * ks][3]);
            pk.u[2] = pack_bf2(x[2 * ks + 1][0], x[2 * ks + 1][1]);
            pk.u[3] = pack_bf2(x[2 * ks + 1][2], x[2 * ks + 1][3]);
            af[ks] = pk.v;
        }

        f32x4 acc[8];
        #pragma unroll
        for (int nt = 0; nt < 8; ++nt) acc[nt] = f32x4{0.f, 0.f, 0.f, 0.f};

        #pragma unroll
        for (int ks = 0; ks < 8; ++ks) {
            #pragma unroll
            for (int nt = 0; nt < 8; ++nt) {
                acc[nt] = __builtin_amdgcn_mfma_f32_16x16x32_bf16(
                    af[ks], bl[(nt * 8 + ks) * 64 + lane], acc[nt], 0, 0, 0);
            }
        }

        // Epilogue: D[row][col], row = 4q + reg, col = 16*nt + c
        float part0 = 0.f, part1 = 0.f, part2 = 0.f, part3 = 0.f;
        #pragma unroll
        for (int nt = 0; nt < 8; ++nt) {
            const float vv = Vv[nt], wd = w2dv[nt];
            part0 += vv * tanhf(acc[nt][0] + wd);
            part1 += vv * tanhf(acc[nt][1] + wd);
            part2 += vv * tanhf(acc[nt][2] + wd);
            part3 += vv * tanhf(acc[nt][3] + wd);
        }
        // Reduce over the 16 lanes (c = 0..15) of this lane-group
        #pragma unroll
        for (int m = 1; m < 16; m <<= 1) {
            part0 += __shfl_xor(part0, m, 64);
            part1 += __shfl_xor(part1, m, 64);
            part2 += __shfl_xor(part2, m, 64);
            part3 += __shfl_xor(part3, m, 64);
        }
        if (c == 0) {
            float4 st;
            st.x = part0; st.y = part1; st.z = part2; st.w = part3;
            *(float4*)(out + (size_t)b * T_ + (tbase + q * 4)) = st;
        }
    }
}

extern "C" void kernel_launch(void* const* d_in, const int* in_sizes, int n_in,
                              void* d_out, int out_size, void* d_ws, size_t ws_size,
                              hipStream_t stream) {
    const float* enc = (const float*)d_in[0];
    const float* dec = (const float*)d_in[1];
    const float* W1  = (const float*)d_in[2];
    const float* W2  = (const float*)d_in[3];
    const float* V   = (const float*)d_in[4];
    float* out = (float*)d_out;

    float* w2d   = (float*)d_ws;
    uint4* frags = (uint4*)((char*)d_ws + 16384);

    prep_kernel<<<48, 256, 0, stream>>>(dec, W1, W2, w2d, frags);
    attn_main<<<512, 256, 0, stream>>>(enc, V, w2d, frags, out);
}

// Round 3
// 65.343 us; speedup vs baseline: 1.8732x; 1.8732x over previous
//
#include <hip/hip_runtime.h>

#define B_ 32
#define T_ 8192
#define F_ 256
#define H_ 128

typedef short bf16x8 __attribute__((ext_vector_type(8)));
typedef float f32x4  __attribute__((ext_vector_type(4)));

// float -> bf16 round-to-nearest-even (normal values; inputs are Gaussian)
static __device__ __forceinline__ unsigned int f2bf(float x) {
    unsigned int u = __builtin_bit_cast(unsigned int, x);
    u += 0x7fffu + ((u >> 16) & 1u);
    return u >> 16;
}
static __device__ __forceinline__ unsigned int pack_bf2(float lo, float hi) {
    return f2bf(lo) | (f2bf(hi) << 16);
}

// tanh via hardware exp2: |err| ~1e-6, plenty under the 3.2e-2 threshold
static __device__ __forceinline__ float fast_tanh(float x) {
    float cx = fminf(fmaxf(x, -15.f), 15.f);
    float e = __expf(2.f * cx);                 // v_exp_f32
    return 1.f - 2.f * __builtin_amdgcn_rcpf(e + 1.f);
}

// ws layout: [0, 16KB): w2d = dec@W2, fp32 [32][128]
//            [16KB, 80KB): W1 bf16 fragments, 4096 entries * 16B
// Fragment entry e = (nt*8 + ks)*64 + lane ; entry[j] = bf16(W1[f][h])
//   with q = lane>>4, c = lane&15, h = 16*nt + c, f = 64*q + 8*ks + j
__global__ __launch_bounds__(256) void prep_kernel(const float* __restrict__ dec,
                                                   const float* __restrict__ W1,
                                                   const float* __restrict__ W2,
                                                   float* __restrict__ w2d,
                                                   uint4* __restrict__ frags) {
    const int blk = blockIdx.x, tid = threadIdx.x;
    if (blk < 32) {
        if (tid < H_) {
            const float* dp = dec + blk * F_;
            float s = 0.f;
            #pragma unroll 8
            for (int f = 0; f < F_; ++f) s += dp[f] * W2[f * H_ + tid];
            w2d[blk * H_ + tid] = s;
        }
    } else {
        const int e = (blk - 32) * 256 + tid;   // 0..4095
        const int lane = e & 63;
        const int ks   = (e >> 6) & 7;
        const int nt   = e >> 9;
        const int q = lane >> 4, c = lane & 15;
        const int h = nt * 16 + c;
        const float* src = W1 + (q * 64 + ks * 8) * H_ + h;
        unsigned int u[4];
        #pragma unroll
        for (int jj = 0; jj < 4; ++jj) {
            float a = src[(2 * jj) * H_];
            float b = src[(2 * jj + 1) * H_];
            u[jj] = pack_bf2(a, b);
        }
        frags[e] = uint4{u[0], u[1], u[2], u[3]};
    }
}

// Main: 1024 blocks x 256 threads. Block -> (b = blk>>5, t0 = (blk&31)*256).
// 4 tiles of 64 rows. Wave w owns h-columns [32w, 32w+32) with W1 frags in
// registers; encoder staged in LDS (coalesced + XOR-swizzled, 2-way max).
__global__ __launch_bounds__(256) void attn_main(const float* __restrict__ enc,
                                                 const float* __restrict__ Vvec,
                                                 const float* __restrict__ w2d,
                                                 const uint4* __restrict__ frags,
                                                 float* __restrict__ out) {
    __shared__ __align__(16) unsigned char tile_lds[64 * 512];  // 32 KB: 64 rows x 256 bf16
    __shared__ float red[4][64];                                 // cross-wave partials

    const int tid  = threadIdx.x;
    const int blk  = blockIdx.x;
    const int b    = blk >> 5;
    const int t0   = (blk & 31) << 8;
    const int w    = tid >> 6;
    const int lane = tid & 63;
    const int q    = lane >> 4;     // A: k-quarter; D: row-group
    const int c    = lane & 15;     // A: row-in-tile16; D: col-in-ntile

    // W1 B-fragments for this wave's 32 columns: 64 VGPRs, loaded once (coalesced)
    bf16x8 bw[2][8];
    #pragma unroll
    for (int ntl = 0; ntl < 2; ++ntl)
        #pragma unroll
        for (int ks = 0; ks < 8; ++ks) {
            uint4 u = frags[((2 * w + ntl) * 8 + ks) * 64 + lane];
            bw[ntl][ks] = __builtin_bit_cast(bf16x8, u);
        }

    float Vv[2], wd[2];
    #pragma unroll
    for (int ntl = 0; ntl < 2; ++ntl) {
        const int h = 16 * (2 * w + ntl) + c;
        Vv[ntl] = Vvec[h];
        wd[ntl] = w2d[b * H_ + h];
    }

    const f32x4* src = (const f32x4*)(enc + ((size_t)b * T_ + t0) * F_);
    const int sw = c & 7;

    for (int ti = 0; ti < 4; ++ti) {
        // ---- stage 64 rows, coalesced f32x4 loads -> bf16 -> swizzled LDS ----
        const f32x4* sp = src + ti * 4096;
        #pragma unroll
        for (int half = 0; half < 2; ++half) {
            f32x4 x[8];
            #pragma unroll
            for (int i = 0; i < 8; ++i) x[i] = sp[(half * 8 + i) * 256 + tid];
            #pragma unroll
            for (int i = 0; i < 8; ++i) {
                const int flat4 = (half * 8 + i) * 256 + tid;  // 0..4095
                const int row   = flat4 >> 6;                  // 0..63
                const int c4    = flat4 & 63;                  // f32x4 chunk in row
                const int chunk = (c4 >> 1) ^ (row & 7);       // 16B-chunk swizzle
                uint2 v;
                v.x = pack_bf2(x[i][0], x[i][1]);
                v.y = pack_bf2(x[i][2], x[i][3]);
                *(uint2*)(tile_lds + row * 512 + chunk * 16 + (c4 & 1) * 8) = v;
            }
        }
        __syncthreads();

        // ---- compute: 4 row-groups of 16; K=256 via 8 MFMA steps x 2 ntiles ----
        #pragma unroll
        for (int g = 0; g < 4; ++g) {
            const unsigned char* rbase = tile_lds + (g * 16 + c) * 512;
            f32x4 acc0 = {0.f, 0.f, 0.f, 0.f};
            f32x4 acc1 = {0.f, 0.f, 0.f, 0.f};
            #pragma unroll
            for (int ks = 0; ks < 8; ++ks) {
                bf16x8 a = *(const bf16x8*)(rbase + ((8 * q + ks) ^ sw) * 16);
                acc0 = __builtin_amdgcn_mfma_f32_16x16x32_bf16(a, bw[0][ks], acc0, 0, 0, 0);
                acc1 = __builtin_amdgcn_mfma_f32_16x16x32_bf16(a, bw[1][ks], acc1, 0, 0, 0);
            }
            float part[4];
            #pragma unroll
            for (int r = 0; r < 4; ++r)
                part[r] = Vv[0] * fast_tanh(acc0[r] + wd[0])
                        + Vv[1] * fast_tanh(acc1[r] + wd[1]);
            #pragma unroll
            for (int m = 1; m < 16; m <<= 1) {
                #pragma unroll
                for (int r = 0; r < 4; ++r) part[r] += __shfl_xor(part[r], m, 64);
            }
            if (c == 0) {
                #pragma unroll
                for (int r = 0; r < 4; ++r) red[w][g * 16 + 4 * q + r] = part[r];
            }
        }
        __syncthreads();

        // ---- combine 4 wave-partials, store 64 rows ----
        if (tid < 64) {
            float s = red[0][tid] + red[1][tid] + red[2][tid] + red[3][tid];
            out[(size_t)b * T_ + t0 + ti * 64 + tid] = s;
        }
    }
}

extern "C" void kernel_launch(void* const* d_in, const int* in_sizes, int n_in,
                              void* d_out, int out_size, void* d_ws, size_t ws_size,
                              hipStream_t stream) {
    const float* enc = (const float*)d_in[0];
    const float* dec = (const float*)d_in[1];
    const float* W1  = (const float*)d_in[2];
    const float* W2  = (const float*)d_in[3];
    const float* V   = (const float*)d_in[4];
    float* out = (float*)d_out;

    float* w2d   = (float*)d_ws;
    uint4* frags = (uint4*)((char*)d_ws + 16384);

    prep_kernel<<<48, 256, 0, stream>>>(dec, W1, W2, w2d, frags);
    attn_main<<<1024, 256, 0, stream>>>(enc, V, w2d, frags, out);
}

// Round 4
// 60.644 us; speedup vs baseline: 2.0184x; 1.0775x over previous
//
#include <hip/hip_runtime.h>

#define B_ 32
#define T_ 8192
#define F_ 256
#define H_ 128

typedef short bf16x8 __attribute__((ext_vector_type(8)));
typedef float f32x4  __attribute__((ext_vector_type(4)));

// float -> bf16 round-to-nearest-even (normal values; inputs are Gaussian)
static __device__ __forceinline__ unsigned int f2bf(float x) {
    unsigned int u = __builtin_bit_cast(unsigned int, x);
    u += 0x7fffu + ((u >> 16) & 1u);
    return u >> 16;
}
static __device__ __forceinline__ unsigned int pack_bf2(float lo, float hi) {
    return f2bf(lo) | (f2bf(hi) << 16);
}

// tanh via hardware exp2: |err| ~1e-6, plenty under the 3.2e-2 threshold
static __device__ __forceinline__ float fast_tanh(float x) {
    float cx = fminf(fmaxf(x, -15.f), 15.f);
    float e = __expf(2.f * cx);                 // v_exp_f32
    return 1.f - 2.f * __builtin_amdgcn_rcpf(e + 1.f);
}

// ws layout: [0, 16KB): w2d = dec@W2, fp32 [32][128]
//            [16KB, 80KB): W1 bf16 fragments, 4096 entries * 16B
// Fragment entry e = (nt*8 + ks)*64 + lane ; entry[j] = bf16(W1[f][h])
//   with q = lane>>4, c = lane&15, h = 16*nt + c, f = 64*q + 8*ks + j
__global__ __launch_bounds__(256) void prep_kernel(const float* __restrict__ dec,
                                                   const float* __restrict__ W1,
                                                   const float* __restrict__ W2,
                                                   float* __restrict__ w2d,
                                                   uint4* __restrict__ frags) {
    const int blk = blockIdx.x, tid = threadIdx.x;
    if (blk < 32) {
        if (tid < H_) {
            const float* dp = dec + blk * F_;
            float s = 0.f;
            #pragma unroll 8
            for (int f = 0; f < F_; ++f) s += dp[f] * W2[f * H_ + tid];
            w2d[blk * H_ + tid] = s;
        }
    } else {
        const int e = (blk - 32) * 256 + tid;   // 0..4095
        const int lane = e & 63;
        const int ks   = (e >> 6) & 7;
        const int nt   = e >> 9;
        const int q = lane >> 4, c = lane & 15;
        const int h = nt * 16 + c;
        const float* src = W1 + (q * 64 + ks * 8) * H_ + h;
        unsigned int u[4];
        #pragma unroll
        for (int jj = 0; jj < 4; ++jj) {
            float a = src[(2 * jj) * H_];
            float b = src[(2 * jj + 1) * H_];
            u[jj] = pack_bf2(a, b);
        }
        frags[e] = uint4{u[0], u[1], u[2], u[3]};
    }
}

// Main: 1024 blocks x 256 threads. Block -> (b = blk>>5, t0 = (blk&31)*256).
// 8 half-tiles of 32 rows, double-buffered LDS, 1 barrier per half-tile.
// Wave w owns h-columns [32w, 32w+32) with W1 frags in registers.
__global__ __launch_bounds__(256) void attn_main(const float* __restrict__ enc,
                                                 const float* __restrict__ Vvec,
                                                 const float* __restrict__ w2d,
                                                 const uint4* __restrict__ frags,
                                                 float* __restrict__ out) {
    __shared__ __align__(16) unsigned char tile_lds[2][32 * 512]; // 2 x 16 KB
    __shared__ float red[4][256];                                 // per-wave row partials

    const int tid  = threadIdx.x;
    const int blk  = blockIdx.x;
    const int b    = blk >> 5;
    const int t0   = (blk & 31) << 8;
    const int w    = tid >> 6;
    const int lane = tid & 63;
    const int q    = lane >> 4;     // A: k-quarter; D: row-group
    const int c    = lane & 15;     // A: row-in-tile16; D: col-in-ntile

    // W1 B-fragments for this wave's 32 columns: 64 VGPRs, loaded once (coalesced)
    bf16x8 bw[2][8];
    #pragma unroll
    for (int ntl = 0; ntl < 2; ++ntl)
        #pragma unroll
        for (int ks = 0; ks < 8; ++ks) {
            uint4 u = frags[((2 * w + ntl) * 8 + ks) * 64 + lane];
            bw[ntl][ks] = __builtin_bit_cast(bf16x8, u);
        }

    float Vv[2], wd[2];
    #pragma unroll
    for (int ntl = 0; ntl < 2; ++ntl) {
        const int h = 16 * (2 * w + ntl) + c;
        Vv[ntl] = Vvec[h];
        wd[ntl] = w2d[b * H_ + h];
    }

    const f32x4* src = (const f32x4*)(enc + ((size_t)b * T_ + t0) * F_);
    const int sw = c & 7;

    // Prologue: issue loads for half-tile 0 (8 coalesced dwordx4 per thread)
    f32x4 x[8];
    #pragma unroll
    for (int i = 0; i < 8; ++i) x[i] = src[i * 256 + tid];

    for (int ht = 0; ht < 8; ++ht) {
        const int cur = ht & 1;
        unsigned char* buf = tile_lds[cur];

        // ---- pack regs -> bf16 -> swizzled LDS (frees x) ----
        #pragma unroll
        for (int i = 0; i < 8; ++i) {
            const int flat4 = i * 256 + tid;   // 0..2047
            const int row   = flat4 >> 6;      // 0..31
            const int c4    = flat4 & 63;      // f32x4 chunk in row
            const int chunk = (c4 >> 1) ^ (row & 7);
            uint2 v;
            v.x = pack_bf2(x[i][0], x[i][1]);
            v.y = pack_bf2(x[i][2], x[i][3]);
            *(uint2*)(buf + row * 512 + chunk * 16 + (c4 & 1) * 8) = v;
        }

        // ---- issue next half-tile's global loads (land during compute) ----
        if (ht < 7) {
            const f32x4* sp = src + (ht + 1) * 2048;
            #pragma unroll
            for (int i = 0; i < 8; ++i) x[i] = sp[i * 256 + tid];
        }

        __syncthreads();   // writes to buf visible; single barrier per iter

        // ---- compute 2 row-groups of 16; K=256 via 8 MFMA steps x 2 ntiles ----
        #pragma unroll
        for (int g = 0; g < 2; ++g) {
            const unsigned char* rbase = buf + (g * 16 + c) * 512;
            f32x4 acc0 = {0.f, 0.f, 0.f, 0.f};
            f32x4 acc1 = {0.f, 0.f, 0.f, 0.f};
            #pragma unroll
            for (int ks = 0; ks < 8; ++ks) {
                bf16x8 a = *(const bf16x8*)(rbase + ((8 * q + ks) ^ sw) * 16);
                acc0 = __builtin_amdgcn_mfma_f32_16x16x32_bf16(a, bw[0][ks], acc0, 0, 0, 0);
                acc1 = __builtin_amdgcn_mfma_f32_16x16x32_bf16(a, bw[1][ks], acc1, 0, 0, 0);
            }
            f32x4 part;
            #pragma unroll
            for (int r = 0; r < 4; ++r)
                part[r] = Vv[0] * fast_tanh(acc0[r] + wd[0])
                        + Vv[1] * fast_tanh(acc1[r] + wd[1]);
            #pragma unroll
            for (int m = 1; m < 16; m <<= 1) {
                #pragma unroll
                for (int r = 0; r < 4; ++r) part[r] += __shfl_xor(part[r], m, 64);
            }
            if (c == 0)
                *(f32x4*)&red[w][ht * 32 + g * 16 + 4 * q] = part;
        }
        // no second barrier: next iter writes the OTHER LDS buffer
    }

    __syncthreads();
    // ---- combine 4 wave-partials for all 256 rows, coalesced store ----
    {
        float s = red[0][tid] + red[1][tid] + red[2][tid] + red[3][tid];
        out[(size_t)b * T_ + t0 + tid] = s;
    }
}

extern "C" void kernel_launch(void* const* d_in, const int* in_sizes, int n_in,
                              void* d_out, int out_size, void* d_ws, size_t ws_size,
                              hipStream_t stream) {
    const float* enc = (const float*)d_in[0];
    const float* dec = (const float*)d_in[1];
    const float* W1  = (const float*)d_in[2];
    const float* W2  = (const float*)d_in[3];
    const float* V   = (const float*)d_in[4];
    float* out = (float*)d_out;

    float* w2d   = (float*)d_ws;
    uint4* frags = (uint4*)((char*)d_ws + 16384);

    prep_kernel<<<48, 256, 0, stream>>>(dec, W1, W2, w2d, frags);
    attn_main<<<1024, 256, 0, stream>>>(enc, V, w2d, frags, out);
}